// Round 3
// baseline (1249.522 us; speedup 1.0000x reference)
//
#include <hip/hip_runtime.h>
#include <hip/hip_cooperative_groups.h>

// TV denoiser (Chambolle-Pock), 40 iterations = 5 phases x 8 fused steps.
// Temporal blocking: 64x64 staged region -> central 48x48 output (KF=8).
//
// Round-15: SINGLE cooperative launch, persistent registers across phases.
//   Evidence (round-14 counters): VALUBusy 50%, hbm 18%, conflicts 0, and
//   neither occupancy (r13) nor barrier count (r14) moved dur. VALU floor
//   ~22us/phase vs 44.6 measured -> the stall is the lockstep re-staging
//   burst (38.9MB FETCH at 1.46TB/s, 24 scattered loads/thread) + 24us of
//   launch gaps. Fix: a block's central 48x48 regs after phase p are
//   BIT-IDENTICAL to its stores, so only the 16-wide ring (neighbor data)
//   needs reloading. Fuse phases with grid.sync(): phase 0 loads y only;
//   phases 1-4 reload ring only (43.75% of threads); y persists in regs.
//   Co-residency: z-paired images (grid 11x11x4, 2 images/block, fully
//   unrolled -> static reg indices) needs only 2 blocks/CU at <=128 VGPR.
//   Host validates via hipOccupancyMaxActiveBlocksPerMultiprocessor and
//   falls back to 5 plain launches (= round-14 behavior) if coop fails.
//   Buffer ping-pong per phase; grid.sync orders neighbor stores before
//   ring reloads; double-buffered LDS exchange makes in-phase barriers
//   race-free (same argument as r14; image->image transitions use
//   disjoint buffers + the initial-exchange barrier).
//
// Round-12 structure retained: wave = strip, cross-lane via __shfl (VERIFIED
// wave-wide on gfx950; DPP row-shifts mis-shift at 16-lane boundaries).
// 8 waves; wave s owns rows 8s..8s+7 of all 64 staged columns in REGISTERS.
// Vertical neighbors: registers. Horizontal: __shfl_up(u1)/__shfl_down(w).
// Lane-edge clamp garbage harmless (cols lc=0/63 have tm=0, cone argument
// rounds 8-10). Wave-7 halo = zeros. sigBot kills the unique active
// bottom-edge case; fmaf(0,x,u)==u freeze is NaN-safe (operands finite).
// first phase: u==0, x2==y (no memset). last phase: skip u stores.

#define Hh 512
#define Ww 512
#define Bb 8
#define TS 48
#define KF 8
#define S  64
#define NT 512
#define RS 8            // rows per strip = rows per thread
#define NIMG 2          // images per block (z-pairing for coop co-residency)
#define GX ((Ww + TS - 1) / TS)   // 11
#define GY ((Hh + TS - 1) / TS)   // 11
#define GZ (Bb / NIMG)            // 4
#define NCU 256         // MI355X

__global__ __launch_bounds__(NT, 4)   // min 4 waves/EU -> VGPR cap 128
void tv_fused(const float*  __restrict__ y_in,
              float*  __restrict__ x2A, float2* __restrict__ uA,
              float*  __restrict__ x2B, float2* __restrict__ uB,
              float*  __restrict__ outp,
              int pStart, int pEnd)
{
    constexpr float TAU = 0.01f;
    constexpr float RHO = 1.99f;
    constexpr float HRHO = 0.995f;       // 0.5*RHO
    constexpr float SIGMA = 12.5f;       // 1/TAU/8
    constexpr float THS = 0.1f;
    constexpr float INV_1PT = 1.0f / 1.01f;

    // Double-buffered strip-exchange (stride-1, conflict-free, 16 KB):
    __shared__ float uaB[2][8 * S];   // u0 of row 8s-1 (wave s-1 bottom); slot s=0 zeros
    __shared__ float hx2[2][8 * S];   // x2 of row 8(s+1) (wave s+1 row 0); slot s=7 zeros
    __shared__ float hu0[2][8 * S];
    __shared__ float hu1[2][8 * S];

    const int bz  = blockIdx.z;          // 0..3; images bz and bz+4
    const int r0  = blockIdx.y * TS;
    const int c0  = blockIdx.x * TS;
    const int tid = threadIdx.x;

    const int s   = tid >> 6;            // 0..7 == wave id
    const int lc  = tid & 63;            // 0..63 == lane id
    const int gc  = c0 - KF + lc;
    const bool colin = (gc >= 0) & (gc < Ww);
    const float sewf = (gc < Ww - 1) ? SIGMA : 0.f;
    const int lr0 = RS * s;
    const int gr0 = r0 - KF + lr0;
    // ehf==0 on an ACTIVE cell happens only at gr==Hh-1; all other rows frozen.
    const float sigBot = (gr0 + RS - 1 == Hh - 1) ? 0.f : SIGMA;

    if (tid < S) {
        uaB[0][tid] = 0.f;           uaB[1][tid] = 0.f;
        hx2[0][7 * S + tid] = 0.f;   hx2[1][7 * S + tid] = 0.f;
        hu0[0][7 * S + tid] = 0.f;   hu0[1][7 * S + tid] = 0.f;
        hu1[0][7 * S + tid] = 0.f;   hu1[1][7 * S + tid] = 0.f;
    }

    // Persistent per-image state (fully unrolled -> static indices, rule #20)
    float x2[NIMG][RS], u0v[NIMG][RS], u1v[NIMG][RS], yv[NIMG][RS], yvh[NIMG];
    unsigned tmp0 = 0u, tmp1 = 0u;       // tm bytes (geometry-only, image-independent)
    #pragma unroll
    for (int i = 0; i < RS; ++i) {
        const int gr = gr0 + i;
        const int lr = lr0 + i;
        const bool img = colin & (gr >= 0) & (gr < Hh);
        unsigned tm = img ? (unsigned)min(min(lr, S - 1 - lr), min(lc, S - 1 - lc)) : 0u;
        if (i < 4) tmp0 |= tm << (8 * i);
        else       tmp1 |= tm << (8 * (i - 4));
    }

    for (int p = pStart; p <= pEnd; ++p) {
        const bool first = (p == 0);
        const bool last  = (p == 4);
        const bool full  = (p == pStart);    // full stage only on entry phase
        const float* x2i; const float2* ui; float* x2o; float2* uo;
        if (p & 1) { x2i = x2A; ui = uA; x2o = x2B; uo = uB; }
        else       { x2i = x2B; ui = uB; x2o = x2A; uo = uA; }
        if (last) x2o = outp;

        #pragma unroll
        for (int im = 0; im < NIMG; ++im) {
            const size_t plane = (size_t)(bz + GZ * im) * (size_t)(Hh * Ww);

            // ---- stage
            if (full) {
                #pragma unroll
                for (int i = 0; i < RS; ++i) {
                    const int gr = gr0 + i;
                    const bool img = colin & (gr >= 0) & (gr < Hh);
                    const size_t gi = plane + (size_t)gr * Ww + gc;
                    float c = img ? y_in[gi] : 0.f;
                    yv[im][i] = c;
                    float a, z0, z1;
                    if (first) { a = c; z0 = 0.f; z1 = 0.f; }
                    else {
                        a = img ? x2i[gi] : 0.f;
                        float2 uu = img ? ui[gi] : make_float2(0.f, 0.f);
                        z0 = uu.x; z1 = uu.y;
                    }
                    x2[im][i] = a; u0v[im][i] = z0; u1v[im][i] = z1;
                }
                const int grh = gr0 + RS;
                yvh[im] = ((s < 7) & colin & (grh < Hh))
                        ? y_in[plane + (size_t)grh * Ww + gc] : 0.f;
            } else {
                // ring reload only: central regs == stored bytes (bit-exact)
                const bool ringT = (s == 0) | (s == 7) | (lc < KF) | (lc >= KF + TS);
                if (ringT) {
                    #pragma unroll
                    for (int i = 0; i < RS; ++i) {
                        const int gr = gr0 + i;
                        const bool img = colin & (gr >= 0) & (gr < Hh);
                        const size_t gi = plane + (size_t)gr * Ww + gc;
                        x2[im][i] = img ? x2i[gi] : 0.f;
                        float2 uu = img ? ui[gi] : make_float2(0.f, 0.f);
                        u0v[im][i] = uu.x; u1v[im][i] = uu.y;
                    }
                }
            }

            // ---- initial exchange into buffer 0
            if (s < 7) uaB[0][(s + 1) * S + lc] = u0v[im][RS - 1];
            if (s > 0) {
                hx2[0][(s - 1) * S + lc] = x2[im][0];
                hu0[0][(s - 1) * S + lc] = u0v[im][0];
                hu1[0][(s - 1) * S + lc] = u1v[im][0];
            }
            __syncthreads();

            // ---- 8 timesteps, one barrier each (round-14 structure)
            float w[RS];
            for (int t = 0; t < KF; ++t) {
                const int rb = t & 1;
                const int wb = rb ^ 1;
                float ua0 = uaB[rb][s * S + lc];
                float x2h = hx2[rb][s * S + lc];
                float u0h = hu0[rb][s * S + lc];
                float u1h = hu1[rb][s * S + lc];

                #pragma unroll
                for (int i = 0; i < RS; ++i) {
                    float ul = __shfl_up(u1v[im][i], 1, 64);
                    float ua = (i == 0) ? ua0 : u0v[im][i - 1];
                    float adj = ua - u0v[im][i] + ul - u1v[im][i];
                    float xv = fmaf(TAU, yv[im][i] - adj, x2[im][i]);
                    w[i] = fmaf(2.0f * INV_1PT, xv, -x2[im][i]);
                }
                float wh;   // halo w == wave s+1's w[0], identical inputs+order
                {
                    float ul = __shfl_up(u1h, 1, 64);
                    float adj = u0v[im][RS - 1] - u0h + ul - u1h;
                    float xv = fmaf(TAU, yvh[im] - adj, x2h);
                    wh = fmaf(2.0f * INV_1PT, xv, -x2h);
                }

                #pragma unroll
                for (int i = 0; i < RS; ++i) {
                    float wr = __shfl_down(w[i], 1, 64);
                    float wbv = (i == RS - 1) ? wh : w[i + 1];
                    const float sig_h = (i == RS - 1) ? sigBot : SIGMA;
                    float v0 = fmaf(sig_h, wbv - w[i], u0v[im][i]);
                    float v1 = fmaf(sewf,  wr - w[i], u1v[im][i]);
                    float iv = fminf(THS * __builtin_amdgcn_rsqf(fmaf(v0, v0, v1 * v1)), 1.f);
                    unsigned tmb = ((i < 4 ? tmp0 : tmp1) >> (8 * (i & 3))) & 255u;
                    bool act = (unsigned)t < tmb;
                    float r1 = act ? RHO  : 0.f;
                    float rh = act ? HRHO : 0.f;
                    u0v[im][i] = fmaf(r1, fmaf(v0, iv, -u0v[im][i]), u0v[im][i]);
                    u1v[im][i] = fmaf(r1, fmaf(v1, iv, -u1v[im][i]), u1v[im][i]);
                    x2[im][i]  = fmaf(rh, w[i] - x2[im][i], x2[im][i]);
                }
                if (t < KF - 1) {
                    if (s < 7) uaB[wb][(s + 1) * S + lc] = u0v[im][RS - 1];
                    if (s > 0) {
                        hx2[wb][(s - 1) * S + lc] = x2[im][0];
                        hu0[wb][(s - 1) * S + lc] = u0v[im][0];
                        hu1[wb][(s - 1) * S + lc] = u1v[im][0];
                    }
                    __syncthreads();
                }
            }

            // ---- store central 48x48 straight from registers
            if (s >= 1 && s <= 6 && lc >= KF && lc < KF + TS && gc < Ww) {
                #pragma unroll
                for (int i = 0; i < RS; ++i) {
                    const int gr = gr0 + i;
                    if (gr < Hh) {
                        const size_t gi = plane + (size_t)gr * Ww + gc;
                        x2o[gi] = x2[im][i];
                        if (!last) uo[gi] = make_float2(u0v[im][i], u1v[im][i]);
                    }
                }
            }
        } // im

        if (p < pEnd) cooperative_groups::this_grid().sync();
    } // p
}

extern "C" void kernel_launch(void* const* d_in, const int* in_sizes, int n_in,
                              void* d_out, int out_size, void* d_ws, size_t ws_size,
                              hipStream_t stream)
{
    const float* y = (const float*)d_in[0];
    float* out = (float*)d_out;
    const size_t NP = (size_t)Bb * Hh * Ww;   // 2M cells

    float*  ws  = (float*)d_ws;
    float*  x2A = ws;                          // 8 MB
    float*  x2B = ws + NP;                     // 8 MB
    float2* uA  = (float2*)(ws + 2 * NP);      // 16 MB
    float2* uB  = (float2*)(ws + 4 * NP);      // 16 MB
    // total ws use: 48 MB; no memset (phase 0 treats u as 0, x2 as y)

    dim3 grid(GX, GY, GZ);                     // 11 x 11 x 4 = 484 blocks
    const int nBlocks = GX * GY * GZ;

    // Cooperative path: needs all 484 blocks co-resident (2 blocks/CU).
    int maxB = 0;
    hipError_t qe = hipOccupancyMaxActiveBlocksPerMultiprocessor(
                        &maxB, (const void*)tv_fused, NT, 0);
    if (qe == hipSuccess && maxB * NCU >= nBlocks) {
        int p0 = 0, p1 = 4;
        void* args[] = { (void*)&y, (void*)&x2A, (void*)&uA,
                         (void*)&x2B, (void*)&uB, (void*)&out, &p0, &p1 };
        hipError_t le = hipLaunchCooperativeKernel((const void*)tv_fused,
                                                   grid, dim3(NT), args, 0, stream);
        if (le == hipSuccess) return;
    }

    // Fallback: 5 plain launches (grid.sync never executed when pStart==pEnd)
    tv_fused<<<grid, NT, 0, stream>>>(y, x2A, uA, x2B, uB, out, 0, 0);
    tv_fused<<<grid, NT, 0, stream>>>(y, x2A, uA, x2B, uB, out, 1, 1);
    tv_fused<<<grid, NT, 0, stream>>>(y, x2A, uA, x2B, uB, out, 2, 2);
    tv_fused<<<grid, NT, 0, stream>>>(y, x2A, uA, x2B, uB, out, 3, 3);
    tv_fused<<<grid, NT, 0, stream>>>(y, x2A, uA, x2B, uB, out, 4, 4);
}

// Round 4
// 706.001 us; speedup vs baseline: 1.7699x; 1.7699x over previous
//
#include <hip/hip_runtime.h>
#include <hip/hip_cooperative_groups.h>

// TV denoiser (Chambolle-Pock), 40 iterations = 5 phases x 8 fused steps.
// Temporal blocking: 64x64 staged region -> central 48x48 output (KF=8).
//
// Round-16: round-15 coop structure with the CORRECT register budget.
//   Round-15 post-mortem: __launch_bounds__(512,4) -> compiler treats 2nd
//   arg as BLOCKS/CU on this toolchain (rounds 8/9 evidence) -> 64-VGPR cap
//   -> NIMG=2 persistent state (~95 floats) spilled to scratch: VGPR=64,
//   FETCH 1.07 GB/dispatch, VALUBusy 9%, 890 us. The coop theory was never
//   tested. Fix: __launch_bounds__(512,2) -> 2 blocks/CU -> 128-VGPR cap.
//   484 blocks / 256 CU = 1.89 -> 2 blocks/CU co-residency suffices.
//   SPILL SENTINEL: coop dispatch FETCH must be ~100-130 MB, not GBs.
//
// Round-15 rationale (evidence from round-14 counters: VALUBusy 50%, hbm
// 18%, conflicts 0; occupancy (r13) and barrier count (r14) both neutral):
//   VALU floor ~22us/phase vs 44.6 measured -> stall is the lockstep
//   re-staging burst (38.9MB FETCH at 1.46TB/s, 24 scattered loads/thread)
//   + ~24us launch gaps. A block's central 48x48 regs after phase p are
//   BIT-IDENTICAL to its stores, so only the 16-wide ring (neighbor data)
//   needs reloading. Fuse phases with grid.sync(): phase 0 loads y only;
//   phases 1-4 reload ring only (43.75% of threads); y persists in regs.
//   Co-residency via z-paired images (grid 11x11x4, NIMG=2, fully unrolled
//   -> static reg indices, rule #20). Host validates occupancy and falls
//   back to 5 plain launches (= round-14 behavior) if coop cannot launch.
//   grid.sync orders neighbor stores before ring reloads; double-buffered
//   LDS exchange keeps in-phase barriers race-free; image->image
//   transitions use disjoint buffer slots + the initial-exchange barrier.
//
// Round-12 structure retained: wave = strip, cross-lane via __shfl (VERIFIED
// wave-wide on gfx950; DPP row-shifts mis-shift at 16-lane boundaries).
// 8 waves; wave s owns rows 8s..8s+7 of all 64 staged columns in REGISTERS.
// Vertical neighbors: registers. Horizontal: __shfl_up(u1)/__shfl_down(w).
// Lane-edge clamp garbage harmless (cols lc=0/63 have tm=0, cone argument
// rounds 8-10). Wave-7 halo = zeros. sigBot kills the unique active
// bottom-edge case; fmaf(0,x,u)==u freeze is NaN-safe (operands finite).
// first phase: u==0, x2==y (no memset). last phase: skip u stores.

#define Hh 512
#define Ww 512
#define Bb 8
#define TS 48
#define KF 8
#define S  64
#define NT 512
#define RS 8            // rows per strip = rows per thread
#define NIMG 2          // images per block (z-pairing for coop co-residency)
#define GX ((Ww + TS - 1) / TS)   // 11
#define GY ((Hh + TS - 1) / TS)   // 11
#define GZ (Bb / NIMG)            // 4
#define NCU 256         // MI355X

__global__ __launch_bounds__(NT, 2)   // 2 blocks/CU (empirical semantics) -> 128-VGPR cap
void tv_fused(const float*  __restrict__ y_in,
              float*  __restrict__ x2A, float2* __restrict__ uA,
              float*  __restrict__ x2B, float2* __restrict__ uB,
              float*  __restrict__ outp,
              int pStart, int pEnd)
{
    constexpr float TAU = 0.01f;
    constexpr float RHO = 1.99f;
    constexpr float HRHO = 0.995f;       // 0.5*RHO
    constexpr float SIGMA = 12.5f;       // 1/TAU/8
    constexpr float THS = 0.1f;
    constexpr float INV_1PT = 1.0f / 1.01f;

    // Double-buffered strip-exchange (stride-1, conflict-free, 16 KB):
    __shared__ float uaB[2][8 * S];   // u0 of row 8s-1 (wave s-1 bottom); slot s=0 zeros
    __shared__ float hx2[2][8 * S];   // x2 of row 8(s+1) (wave s+1 row 0); slot s=7 zeros
    __shared__ float hu0[2][8 * S];
    __shared__ float hu1[2][8 * S];

    const int bz  = blockIdx.z;          // 0..3; images bz and bz+4
    const int r0  = blockIdx.y * TS;
    const int c0  = blockIdx.x * TS;
    const int tid = threadIdx.x;

    const int s   = tid >> 6;            // 0..7 == wave id
    const int lc  = tid & 63;            // 0..63 == lane id
    const int gc  = c0 - KF + lc;
    const bool colin = (gc >= 0) & (gc < Ww);
    const float sewf = (gc < Ww - 1) ? SIGMA : 0.f;
    const int lr0 = RS * s;
    const int gr0 = r0 - KF + lr0;
    // ehf==0 on an ACTIVE cell happens only at gr==Hh-1; all other rows frozen.
    const float sigBot = (gr0 + RS - 1 == Hh - 1) ? 0.f : SIGMA;

    if (tid < S) {
        uaB[0][tid] = 0.f;           uaB[1][tid] = 0.f;
        hx2[0][7 * S + tid] = 0.f;   hx2[1][7 * S + tid] = 0.f;
        hu0[0][7 * S + tid] = 0.f;   hu0[1][7 * S + tid] = 0.f;
        hu1[0][7 * S + tid] = 0.f;   hu1[1][7 * S + tid] = 0.f;
    }

    // Persistent per-image state (fully unrolled -> static indices, rule #20)
    float x2[NIMG][RS], u0v[NIMG][RS], u1v[NIMG][RS], yv[NIMG][RS], yvh[NIMG];
    unsigned tmp0 = 0u, tmp1 = 0u;       // tm bytes (geometry-only, image-independent)
    #pragma unroll
    for (int i = 0; i < RS; ++i) {
        const int gr = gr0 + i;
        const int lr = lr0 + i;
        const bool img = colin & (gr >= 0) & (gr < Hh);
        unsigned tm = img ? (unsigned)min(min(lr, S - 1 - lr), min(lc, S - 1 - lc)) : 0u;
        if (i < 4) tmp0 |= tm << (8 * i);
        else       tmp1 |= tm << (8 * (i - 4));
    }

    for (int p = pStart; p <= pEnd; ++p) {
        const bool first = (p == 0);
        const bool last  = (p == 4);
        const bool full  = (p == pStart);    // full stage only on entry phase
        const float* x2i; const float2* ui; float* x2o; float2* uo;
        if (p & 1) { x2i = x2A; ui = uA; x2o = x2B; uo = uB; }
        else       { x2i = x2B; ui = uB; x2o = x2A; uo = uA; }
        if (last) x2o = outp;

        #pragma unroll
        for (int im = 0; im < NIMG; ++im) {
            const size_t plane = (size_t)(bz + GZ * im) * (size_t)(Hh * Ww);

            // ---- stage
            if (full) {
                #pragma unroll
                for (int i = 0; i < RS; ++i) {
                    const int gr = gr0 + i;
                    const bool img = colin & (gr >= 0) & (gr < Hh);
                    const size_t gi = plane + (size_t)gr * Ww + gc;
                    float c = img ? y_in[gi] : 0.f;
                    yv[im][i] = c;
                    float a, z0, z1;
                    if (first) { a = c; z0 = 0.f; z1 = 0.f; }
                    else {
                        a = img ? x2i[gi] : 0.f;
                        float2 uu = img ? ui[gi] : make_float2(0.f, 0.f);
                        z0 = uu.x; z1 = uu.y;
                    }
                    x2[im][i] = a; u0v[im][i] = z0; u1v[im][i] = z1;
                }
                const int grh = gr0 + RS;
                yvh[im] = ((s < 7) & colin & (grh < Hh))
                        ? y_in[plane + (size_t)grh * Ww + gc] : 0.f;
            } else {
                // ring reload only: central regs == stored bytes (bit-exact)
                const bool ringT = (s == 0) | (s == 7) | (lc < KF) | (lc >= KF + TS);
                if (ringT) {
                    #pragma unroll
                    for (int i = 0; i < RS; ++i) {
                        const int gr = gr0 + i;
                        const bool img = colin & (gr >= 0) & (gr < Hh);
                        const size_t gi = plane + (size_t)gr * Ww + gc;
                        x2[im][i] = img ? x2i[gi] : 0.f;
                        float2 uu = img ? ui[gi] : make_float2(0.f, 0.f);
                        u0v[im][i] = uu.x; u1v[im][i] = uu.y;
                    }
                }
            }

            // ---- initial exchange into buffer 0
            if (s < 7) uaB[0][(s + 1) * S + lc] = u0v[im][RS - 1];
            if (s > 0) {
                hx2[0][(s - 1) * S + lc] = x2[im][0];
                hu0[0][(s - 1) * S + lc] = u0v[im][0];
                hu1[0][(s - 1) * S + lc] = u1v[im][0];
            }
            __syncthreads();

            // ---- 8 timesteps, one barrier each (round-14 structure)
            float w[RS];
            for (int t = 0; t < KF; ++t) {
                const int rb = t & 1;
                const int wb = rb ^ 1;
                float ua0 = uaB[rb][s * S + lc];
                float x2h = hx2[rb][s * S + lc];
                float u0h = hu0[rb][s * S + lc];
                float u1h = hu1[rb][s * S + lc];

                #pragma unroll
                for (int i = 0; i < RS; ++i) {
                    float ul = __shfl_up(u1v[im][i], 1, 64);
                    float ua = (i == 0) ? ua0 : u0v[im][i - 1];
                    float adj = ua - u0v[im][i] + ul - u1v[im][i];
                    float xv = fmaf(TAU, yv[im][i] - adj, x2[im][i]);
                    w[i] = fmaf(2.0f * INV_1PT, xv, -x2[im][i]);
                }
                float wh;   // halo w == wave s+1's w[0], identical inputs+order
                {
                    float ul = __shfl_up(u1h, 1, 64);
                    float adj = u0v[im][RS - 1] - u0h + ul - u1h;
                    float xv = fmaf(TAU, yvh[im] - adj, x2h);
                    wh = fmaf(2.0f * INV_1PT, xv, -x2h);
                }

                #pragma unroll
                for (int i = 0; i < RS; ++i) {
                    float wr = __shfl_down(w[i], 1, 64);
                    float wbv = (i == RS - 1) ? wh : w[i + 1];
                    const float sig_h = (i == RS - 1) ? sigBot : SIGMA;
                    float v0 = fmaf(sig_h, wbv - w[i], u0v[im][i]);
                    float v1 = fmaf(sewf,  wr - w[i], u1v[im][i]);
                    float iv = fminf(THS * __builtin_amdgcn_rsqf(fmaf(v0, v0, v1 * v1)), 1.f);
                    unsigned tmb = ((i < 4 ? tmp0 : tmp1) >> (8 * (i & 3))) & 255u;
                    bool act = (unsigned)t < tmb;
                    float r1 = act ? RHO  : 0.f;
                    float rh = act ? HRHO : 0.f;
                    u0v[im][i] = fmaf(r1, fmaf(v0, iv, -u0v[im][i]), u0v[im][i]);
                    u1v[im][i] = fmaf(r1, fmaf(v1, iv, -u1v[im][i]), u1v[im][i]);
                    x2[im][i]  = fmaf(rh, w[i] - x2[im][i], x2[im][i]);
                }
                if (t < KF - 1) {
                    if (s < 7) uaB[wb][(s + 1) * S + lc] = u0v[im][RS - 1];
                    if (s > 0) {
                        hx2[wb][(s - 1) * S + lc] = x2[im][0];
                        hu0[wb][(s - 1) * S + lc] = u0v[im][0];
                        hu1[wb][(s - 1) * S + lc] = u1v[im][0];
                    }
                    __syncthreads();
                }
            }

            // ---- store central 48x48 straight from registers
            if (s >= 1 && s <= 6 && lc >= KF && lc < KF + TS && gc < Ww) {
                #pragma unroll
                for (int i = 0; i < RS; ++i) {
                    const int gr = gr0 + i;
                    if (gr < Hh) {
                        const size_t gi = plane + (size_t)gr * Ww + gc;
                        x2o[gi] = x2[im][i];
                        if (!last) uo[gi] = make_float2(u0v[im][i], u1v[im][i]);
                    }
                }
            }
        } // im

        if (p < pEnd) cooperative_groups::this_grid().sync();
    } // p
}

extern "C" void kernel_launch(void* const* d_in, const int* in_sizes, int n_in,
                              void* d_out, int out_size, void* d_ws, size_t ws_size,
                              hipStream_t stream)
{
    const float* y = (const float*)d_in[0];
    float* out = (float*)d_out;
    const size_t NP = (size_t)Bb * Hh * Ww;   // 2M cells

    float*  ws  = (float*)d_ws;
    float*  x2A = ws;                          // 8 MB
    float*  x2B = ws + NP;                     // 8 MB
    float2* uA  = (float2*)(ws + 2 * NP);      // 16 MB
    float2* uB  = (float2*)(ws + 4 * NP);      // 16 MB
    // total ws use: 48 MB; no memset (phase 0 treats u as 0, x2 as y)

    dim3 grid(GX, GY, GZ);                     // 11 x 11 x 4 = 484 blocks
    const int nBlocks = GX * GY * GZ;

    // Cooperative path: needs all 484 blocks co-resident (2 blocks/CU).
    int maxB = 0;
    hipError_t qe = hipOccupancyMaxActiveBlocksPerMultiprocessor(
                        &maxB, (const void*)tv_fused, NT, 0);
    if (qe == hipSuccess && maxB * NCU >= nBlocks) {
        int p0 = 0, p1 = 4;
        void* args[] = { (void*)&y, (void*)&x2A, (void*)&uA,
                         (void*)&x2B, (void*)&uB, (void*)&out, &p0, &p1 };
        hipError_t le = hipLaunchCooperativeKernel((const void*)tv_fused,
                                                   grid, dim3(NT), args, 0, stream);
        if (le == hipSuccess) return;
    }

    // Fallback: 5 plain launches (grid.sync never executed when pStart==pEnd)
    tv_fused<<<grid, NT, 0, stream>>>(y, x2A, uA, x2B, uB, out, 0, 0);
    tv_fused<<<grid, NT, 0, stream>>>(y, x2A, uA, x2B, uB, out, 1, 1);
    tv_fused<<<grid, NT, 0, stream>>>(y, x2A, uA, x2B, uB, out, 2, 2);
    tv_fused<<<grid, NT, 0, stream>>>(y, x2A, uA, x2B, uB, out, 3, 3);
    tv_fused<<<grid, NT, 0, stream>>>(y, x2A, uA, x2B, uB, out, 4, 4);
}

// Round 6
// 222.086 us; speedup vs baseline: 5.6263x; 3.1790x over previous
//
#include <hip/hip_runtime.h>

// TV denoiser (Chambolle-Pock), 40 iterations = 5 launches x 8 fused steps.
// Temporal blocking: 64x64 staged region -> central 48x48 output (KF=8).
//
// Round-18: packed float4 per-cell state (x2,u0,u1,y), ping-pong buffers.
//   Coop arc (r15-r17) retired: two spills + one container death (grid.sync
//   deadlock risk); all coop code removed. Back to the proven r13 structure
//   (231.5us; ~22us VALU + ~22us stall per dispatch, VALUBusy 50%, FETCH
//   38.9MB @1.46TB/s). The stall is the lockstep staging burst: 24 scattered
//   load insts/thread. Packing the full cell state into ONE float4 (y rides
//   in .w, static passthrough) cuts it to 8x global_load_dwordx4, stores to
//   one dwordx4. Branchless staging (clamped addr + select) lets edge waves
//   issue all loads back-to-back. Bit-exact: same f32 values round-tripped.
//   Cost: WRITE 24.5->36MB/launch (+1.8us @6.3TB/s), ws 48->64MiB.
//   ws_size GUARD: if ws < 64MiB, run the exact r13 kernel/layout instead.
//   Predicted: 44 -> 34-38us/dispatch, total ~195-210us, VALUBusy ~58%.
//
// Round-12/13 structure retained: wave = strip, cross-lane via __shfl
// (VERIFIED wave-wide on gfx950; DPP row-shifts mis-shift at 16-lane
// boundaries). 512 thr = 8 waves; wave s owns rows 8s..8s+7 of all 64
// staged columns in REGISTERS (thread = one column x 8 rows). Vertical
// neighbors: registers. Horizontal: __shfl_up(u1,1) [ph1] /
// __shfl_down(w,1) [ph2]. Lane-edge clamp garbage harmless: cols lc=0/63
// have tm=0 and feed only inactive cells (cone argument, rounds 8-10).
// Strip boundaries cross waves via stride-1 LDS u0B/wTop (4.6KB,
// conflict-free, single-buffered: read-before-write separated by the two
// per-step barriers). Masks: ph1 unconditional; ph2 freeze via r1/rh=0
// multipliers (NaN-safe: all operands finite, rsq(0)=inf dies in fmin).
// tm byte-packed in 2 VGPRs. sewf/sigBot fold the forward-diff edge masks
// (unique active bottom-edge case by==10,s==4,i==7). first: u=0, x2=y.
// last: store x2 to output only.

#define Hh 512
#define Ww 512
#define Bb 8
#define TS 48
#define KF 8
#define S  64
#define NT 512
#define RS 8           // rows per strip = rows per thread

// ---------------------------------------------------------------- packed --
__global__ __launch_bounds__(NT, 3)
void tv_packed(const float*  __restrict__ y_in,
               const float4* __restrict__ st_in,
               float4* __restrict__ st_out,
               float*  __restrict__ x2_out,
               int first, int last)
{
    constexpr float TAU = 0.01f;
    constexpr float RHO = 1.99f;
    constexpr float HRHO = 0.995f;       // 0.5*RHO
    constexpr float SIGMA = 12.5f;       // 1/TAU/8
    constexpr float THS = 0.1f;
    constexpr float INV_1PT = 1.0f / 1.01f;

    __shared__ float u0B [9 * S];   // u0 of row 8s-1 (strip s-1 bottom); s=0 zeros
    __shared__ float wTop[9 * S];   // w  of row 8s   (strip s top);     s=8 zeros

    const int b   = blockIdx.z;
    const int r0  = blockIdx.y * TS;
    const int c0  = blockIdx.x * TS;
    const int tid = threadIdx.x;
    const size_t plane = (size_t)b * (Hh * Ww);

    const int s   = tid >> 6;            // wave id
    const int lc  = tid & 63;            // lane id
    const int gc  = c0 - KF + lc;
    const bool colin = (gc >= 0) & (gc < Ww);
    const float sewf = (gc < Ww - 1) ? SIGMA : 0.f;
    const int lr0 = RS * s;
    const int gr0 = r0 - KF + lr0;
    const float sigBot = (gr0 + RS - 1 == Hh - 1) ? 0.f : SIGMA;

    if (tid < S) { u0B[tid] = 0.f; wTop[8 * S + tid] = 0.f; }

    float u0[RS], u1[RS], x2[RS], yv[RS], w[RS];
    unsigned tmp0 = 0u, tmp1 = 0u;       // tm bytes

    // ---- stage: branchless, 8 wide loads
    #pragma unroll
    for (int i = 0; i < RS; ++i) {
        const int gr = gr0 + i;
        const int lr = lr0 + i;
        const bool img = colin & (gr >= 0) & (gr < Hh);
        const size_t gi = img ? (plane + (size_t)gr * Ww + gc) : plane;  // clamped, in-bounds
        if (first) {
            float c = y_in[gi];
            c = img ? c : 0.f;
            x2[i] = c; yv[i] = c; u0[i] = 0.f; u1[i] = 0.f;
        } else {
            float4 st = st_in[gi];
            x2[i] = img ? st.x : 0.f;
            u0[i] = img ? st.y : 0.f;
            u1[i] = img ? st.z : 0.f;
            yv[i] = img ? st.w : 0.f;
        }
        unsigned tm = img ? (unsigned)min(min(lr, S - 1 - lr), min(lc, S - 1 - lc)) : 0u;
        if (i < 4) tmp0 |= tm << (8 * i);
        else       tmp1 |= tm << (8 * (i - 4));
    }
    u0B[(s + 1) * S + lc] = u0[RS - 1];
    __syncthreads();

    for (int t = 0; t < KF; ++t) {
        // ---- phase 1: w = 2x - x2 (unconditional)
        {
            float u0a = u0B[s * S + lc];
            #pragma unroll
            for (int i = 0; i < RS; ++i) {
                float ul = __shfl_up(u1[i], 1, 64);
                float ua = (i == 0) ? u0a : u0[i - 1];
                float adj = ua - u0[i] + ul - u1[i];
                float xv = fmaf(TAU, yv[i] - adj, x2[i]);
                w[i] = fmaf(2.0f * INV_1PT, xv, -x2[i]);
            }
            wTop[s * S + lc] = w[0];
        }
        __syncthreads();
        // ---- phase 2: u, x2 update; freeze via r1/rh = 0
        {
            float wbot = wTop[(s + 1) * S + lc];
            #pragma unroll
            for (int i = 0; i < RS; ++i) {
                float wr = __shfl_down(w[i], 1, 64);
                float wb = (i == RS - 1) ? wbot : w[i + 1];
                const float sig_h = (i == RS - 1) ? sigBot : SIGMA;
                float v0 = fmaf(sig_h, wb - w[i], u0[i]);
                float v1 = fmaf(sewf,  wr - w[i], u1[i]);
                float iv = fminf(THS * __builtin_amdgcn_rsqf(fmaf(v0, v0, v1 * v1)), 1.f);
                unsigned tmb = ((i < 4 ? tmp0 : tmp1) >> (8 * (i & 3))) & 255u;
                bool act = (unsigned)t < tmb;
                float r1 = act ? RHO  : 0.f;
                float rh = act ? HRHO : 0.f;
                u0[i] = fmaf(r1, fmaf(v0, iv, -u0[i]), u0[i]);
                u1[i] = fmaf(r1, fmaf(v1, iv, -u1[i]), u1[i]);
                x2[i] = fmaf(rh, w[i] - x2[i], x2[i]);
            }
            u0B[(s + 1) * S + lc] = u0[RS - 1];
        }
        __syncthreads();
    }

    // ---- store central 48x48: one dwordx4 per cell (x2-only on last)
    if (s >= 1 && s <= 6 && lc >= KF && lc < KF + TS && gc < Ww) {
        #pragma unroll
        for (int i = 0; i < RS; ++i) {
            const int gr = gr0 + i;
            if (gr < Hh) {
                const size_t gi = plane + (size_t)gr * Ww + gc;
                if (last) x2_out[gi] = x2[i];
                else      st_out[gi] = make_float4(x2[i], u0[i], u1[i], yv[i]);
            }
        }
    }
}

// ------------------------------------------------- fallback (exact r13) --
__global__ __launch_bounds__(NT, 3)
void tv_sep(const float*  __restrict__ x2_in,
            const float2* __restrict__ u_in,
            const float*  __restrict__ y_in,
            float*  __restrict__ x2_out,
            float2* __restrict__ u_out,
            int first, int last)
{
    constexpr float TAU = 0.01f;
    constexpr float RHO = 1.99f;
    constexpr float HRHO = 0.995f;
    constexpr float SIGMA = 12.5f;
    constexpr float THS = 0.1f;
    constexpr float INV_1PT = 1.0f / 1.01f;

    __shared__ float u0B [9 * S];
    __shared__ float wTop[9 * S];

    const int b   = blockIdx.z;
    const int r0  = blockIdx.y * TS;
    const int c0  = blockIdx.x * TS;
    const int tid = threadIdx.x;
    const size_t plane = (size_t)b * (Hh * Ww);

    const int s   = tid >> 6;
    const int lc  = tid & 63;
    const int gc  = c0 - KF + lc;
    const bool colin = (gc >= 0) & (gc < Ww);
    const float sewf = (gc < Ww - 1) ? SIGMA : 0.f;
    const int lr0 = RS * s;
    const int gr0 = r0 - KF + lr0;
    const float sigBot = (gr0 + RS - 1 == Hh - 1) ? 0.f : SIGMA;

    if (tid < S) { u0B[tid] = 0.f; wTop[8 * S + tid] = 0.f; }

    float u0[RS], u1[RS], x2[RS], yv[RS], w[RS];
    unsigned tmp0 = 0u, tmp1 = 0u;

    #pragma unroll
    for (int i = 0; i < RS; ++i) {
        const int gr = gr0 + i;
        const int lr = lr0 + i;
        const bool img = colin & (gr >= 0) & (gr < Hh);
        float a = 0.f, c = 0.f, z0 = 0.f, z1 = 0.f;
        if (img) {
            size_t gi = plane + (size_t)gr * Ww + gc;
            c = y_in[gi];
            if (first) a = c;
            else {
                a = x2_in[gi];
                float2 uu = u_in[gi];
                z0 = uu.x; z1 = uu.y;
            }
        }
        u0[i] = z0; u1[i] = z1; x2[i] = a; yv[i] = c;
        unsigned tm = img ? (unsigned)min(min(lr, S - 1 - lr), min(lc, S - 1 - lc)) : 0u;
        if (i < 4) tmp0 |= tm << (8 * i);
        else       tmp1 |= tm << (8 * (i - 4));
    }
    u0B[(s + 1) * S + lc] = u0[RS - 1];
    __syncthreads();

    for (int t = 0; t < KF; ++t) {
        {
            float u0a = u0B[s * S + lc];
            #pragma unroll
            for (int i = 0; i < RS; ++i) {
                float ul = __shfl_up(u1[i], 1, 64);
                float ua = (i == 0) ? u0a : u0[i - 1];
                float adj = ua - u0[i] + ul - u1[i];
                float xv = fmaf(TAU, yv[i] - adj, x2[i]);
                w[i] = fmaf(2.0f * INV_1PT, xv, -x2[i]);
            }
            wTop[s * S + lc] = w[0];
        }
        __syncthreads();
        {
            float wbot = wTop[(s + 1) * S + lc];
            #pragma unroll
            for (int i = 0; i < RS; ++i) {
                float wr = __shfl_down(w[i], 1, 64);
                float wb = (i == RS - 1) ? wbot : w[i + 1];
                const float sig_h = (i == RS - 1) ? sigBot : SIGMA;
                float v0 = fmaf(sig_h, wb - w[i], u0[i]);
                float v1 = fmaf(sewf,  wr - w[i], u1[i]);
                float iv = fminf(THS * __builtin_amdgcn_rsqf(fmaf(v0, v0, v1 * v1)), 1.f);
                unsigned tmb = ((i < 4 ? tmp0 : tmp1) >> (8 * (i & 3))) & 255u;
                bool act = (unsigned)t < tmb;
                float r1 = act ? RHO  : 0.f;
                float rh = act ? HRHO : 0.f;
                u0[i] = fmaf(r1, fmaf(v0, iv, -u0[i]), u0[i]);
                u1[i] = fmaf(r1, fmaf(v1, iv, -u1[i]), u1[i]);
                x2[i] = fmaf(rh, w[i] - x2[i], x2[i]);
            }
            u0B[(s + 1) * S + lc] = u0[RS - 1];
        }
        __syncthreads();
    }

    if (s >= 1 && s <= 6 && lc >= KF && lc < KF + TS && gc < Ww) {
        #pragma unroll
        for (int i = 0; i < RS; ++i) {
            const int gr = gr0 + i;
            if (gr < Hh) {
                size_t gi = plane + (size_t)gr * Ww + gc;
                x2_out[gi] = x2[i];
                if (!last) u_out[gi] = make_float2(u0[i], u1[i]);
            }
        }
    }
}

extern "C" void kernel_launch(void* const* d_in, const int* in_sizes, int n_in,
                              void* d_out, int out_size, void* d_ws, size_t ws_size,
                              hipStream_t stream)
{
    const float* y = (const float*)d_in[0];
    float* out = (float*)d_out;
    const size_t NP = (size_t)Bb * Hh * Ww;   // 2M cells

    dim3 grid((Ww + TS - 1) / TS, (Hh + TS - 1) / TS, Bb);   // 11 x 11 x 8 = 968

    if (ws_size >= 2 * NP * sizeof(float4)) {
        // packed path: two 32MiB float4 ping-pong buffers
        float4* stA = (float4*)d_ws;
        float4* stB = stA + NP;
        tv_packed<<<grid, NT, 0, stream>>>(y, stB, stA, out, 1, 0);  // y -> stA
        tv_packed<<<grid, NT, 0, stream>>>(y, stA, stB, out, 0, 0);
        tv_packed<<<grid, NT, 0, stream>>>(y, stB, stA, out, 0, 0);
        tv_packed<<<grid, NT, 0, stream>>>(y, stA, stB, out, 0, 0);
        tv_packed<<<grid, NT, 0, stream>>>(y, stB, stA, out, 0, 1);  // -> out
    } else {
        // fallback: exact r13 layout (48 MiB)
        float*  ws  = (float*)d_ws;
        float*  x2A = ws;
        float*  x2B = ws + NP;
        float2* uA  = (float2*)(ws + 2 * NP);
        float2* uB  = (float2*)(ws + 4 * NP);
        tv_sep<<<grid, NT, 0, stream>>>(y,   uB, y, x2A, uA, 1, 0);
        tv_sep<<<grid, NT, 0, stream>>>(x2A, uA, y, x2B, uB, 0, 0);
        tv_sep<<<grid, NT, 0, stream>>>(x2B, uB, y, x2A, uA, 0, 0);
        tv_sep<<<grid, NT, 0, stream>>>(x2A, uA, y, x2B, uB, 0, 0);
        tv_sep<<<grid, NT, 0, stream>>>(x2B, uB, y, out, uA, 0, 1);
    }
}